// Round 1
// baseline (941.093 us; speedup 1.0000x reference)
//
#include <hip/hip_runtime.h>
#include <hip/hip_bf16.h>
#include <math.h>

#define BM 128
#define BN 128
#define BK 32

typedef __bf16 bf16x8_t __attribute__((ext_vector_type(8)));
typedef __bf16 bf16x4_t __attribute__((ext_vector_type(4)));
typedef float f32x4_t __attribute__((ext_vector_type(4)));

static __device__ __forceinline__ float bf2f(__bf16 b) {
    unsigned short s = __builtin_bit_cast(unsigned short, b);
    unsigned int u = ((unsigned int)s) << 16;
    return __builtin_bit_cast(float, u);
}
static __device__ __forceinline__ __bf16 f2bf(float f) {
    unsigned int u = __builtin_bit_cast(unsigned int, f);
    unsigned int r = (u + 0x7fffu + ((u >> 16) & 1u)) >> 16;
    return __builtin_bit_cast(__bf16, (unsigned short)r);
}
static __device__ __forceinline__ float gelu_exact(float x) {
    return 0.5f * x * (1.0f + erff(x * 0.70710678118654752440f));
}

#define GLDS16(gp, lp)                                                                   \
    __builtin_amdgcn_global_load_lds((const __attribute__((address_space(1))) void*)(gp), \
                                     (__attribute__((address_space(3))) void*)(lp), 16, 0, 0)

// ---------------------------------------------------------------------------
// Transpose+cast: in fp32 [K][N] row-major -> out bf16 [N][K] row-major.
// 64x64 tiles, 256 threads. grid.z indexes experts via strides (elements).
// ---------------------------------------------------------------------------
__global__ __launch_bounds__(256) void transpose_cast(const float* __restrict__ in,
                                                      __bf16* __restrict__ out,
                                                      int K, int N,
                                                      size_t inStride, size_t outStride) {
    in += (size_t)blockIdx.z * inStride;
    out += (size_t)blockIdx.z * outStride;
    __shared__ float tile[64][65];
    const int k0 = blockIdx.x * 64, n0 = blockIdx.y * 64;
    const int tid = threadIdx.x;
    const int r = tid >> 4, c4 = (tid & 15) * 4;
#pragma unroll
    for (int p = 0; p < 4; ++p) {
        const float4 v = *(const float4*)&in[(size_t)(k0 + r + p * 16) * N + n0 + c4];
        tile[r + p * 16][c4 + 0] = v.x;
        tile[r + p * 16][c4 + 1] = v.y;
        tile[r + p * 16][c4 + 2] = v.z;
        tile[r + p * 16][c4 + 3] = v.w;
    }
    __syncthreads();
    const int n = tid >> 2, kc = (tid & 3) * 16;
    bf16x8_t t0, t1;
#pragma unroll
    for (int j = 0; j < 8; ++j) t0[j] = f2bf(tile[kc + j][n]);
#pragma unroll
    for (int j = 0; j < 8; ++j) t1[j] = f2bf(tile[kc + 8 + j][n]);
    __bf16* op = &out[(size_t)(n0 + n) * K + k0 + kc];
    *(bf16x8_t*)op = t0;
    *(bf16x8_t*)(op + 8) = t1;
}

// ---------------------------------------------------------------------------
// Plain cast fp32 -> bf16, 8 elements/thread.
// ---------------------------------------------------------------------------
__global__ __launch_bounds__(256) void cast_kernel(const float* __restrict__ in,
                                                   __bf16* __restrict__ out, int n8) {
    const int i = blockIdx.x * 256 + threadIdx.x;
    if (i < n8) {
        const float4* p = (const float4*)(in + (size_t)i * 8);
        const float4 a = p[0], b = p[1];
        bf16x8_t v;
        v[0] = f2bf(a.x); v[1] = f2bf(a.y); v[2] = f2bf(a.z); v[3] = f2bf(a.w);
        v[4] = f2bf(b.x); v[5] = f2bf(b.y); v[6] = f2bf(b.z); v[7] = f2bf(b.w);
        *(bf16x8_t*)(out + (size_t)i * 8) = v;
    }
}

// ---------------------------------------------------------------------------
// m97-style bf16 GEMM: C[M,N] = act(A[M,K] @ B^T[N,K] + bias), C stored bf16.
// 128x128 tile, BK=32, 256 threads (2x2 waves, each 64x64 via 4x4 MFMA 16x16x32).
// grid.z = expert; strides in elements. ACT: 0 = none, 1 = exact GELU.
// ---------------------------------------------------------------------------
template <int ACT>
__global__ __launch_bounds__(256) void gemm_bt(const __bf16* __restrict__ Ab, int lda, size_t strideAe,
                                               const __bf16* __restrict__ Bb, int ldb, size_t strideBe,
                                               const float* __restrict__ biasb, size_t strideBiasE,
                                               __bf16* __restrict__ Cb, int ldc, size_t strideCe,
                                               int K) {
    __shared__ __bf16 As[BM * BK];
    __shared__ __bf16 Bs[BN * BK];

    const __bf16* A = Ab + (size_t)blockIdx.z * strideAe;
    const __bf16* Bt = Bb + (size_t)blockIdx.z * strideBe;
    const float* bias = biasb + (size_t)blockIdx.z * strideBiasE;
    __bf16* C = Cb + (size_t)blockIdx.z * strideCe;

    const int tid = threadIdx.x;
    const int bm = blockIdx.x, bn = blockIdx.y;
    const int lane = tid & 63, wave = tid >> 6;
    const int wm = wave >> 1, wn = wave & 1;
    const int r = lane & 15, q = lane >> 4;

    // staging: slot = round*256+tid -> LDS row slot>>2, col (slot&3)*8 (contiguous 16B/lane)
    const __bf16* ag = A + (size_t)(bm * BM + (tid >> 2)) * lda + (tid & 3) * 8;
    const __bf16* bg = Bt + (size_t)(bn * BN + (tid >> 2)) * ldb + (tid & 3) * 8;
    __bf16* asl = As + tid * 8;
    __bf16* bsl = Bs + tid * 8;

    const __bf16* afp = As + (wm * 64 + r) * BK + q * 8;
    const __bf16* bfp = Bs + (wn * 64 + r) * BK + q * 8;

    f32x4_t acc[4][4] = {};

    const int nk = K / BK;
    for (int kt = 0; kt < nk; ++kt) {
        GLDS16(ag, asl);
        GLDS16(ag + (size_t)64 * lda, asl + 256 * 8);
        GLDS16(bg, bsl);
        GLDS16(bg + (size_t)64 * ldb, bsl + 256 * 8);
        ag += BK;
        bg += BK;
        __syncthreads();
        bf16x8_t af[4], bf[4];
#pragma unroll
        for (int i = 0; i < 4; ++i) af[i] = *(const bf16x8_t*)(afp + i * 16 * BK);
#pragma unroll
        for (int j = 0; j < 4; ++j) bf[j] = *(const bf16x8_t*)(bfp + j * 16 * BK);
#pragma unroll
        for (int i = 0; i < 4; ++i)
#pragma unroll
            for (int j = 0; j < 4; ++j)
                acc[i][j] = __builtin_amdgcn_mfma_f32_16x16x32_bf16(af[i], bf[j], acc[i][j], 0, 0, 0);
        __syncthreads();
    }

    // epilogue: C/D layout col = lane&15, row = q*4 + v
    const int crow = bm * BM + wm * 64 + q * 4;
    const int ccol = bn * BN + wn * 64 + r;
#pragma unroll
    for (int j = 0; j < 4; ++j) {
        const int col = ccol + j * 16;
        const float bv = bias[col];
#pragma unroll
        for (int i = 0; i < 4; ++i) {
#pragma unroll
            for (int v = 0; v < 4; ++v) {
                float x = acc[i][j][v] + bv;
                if (ACT == 1) x = gelu_exact(x);
                C[(size_t)(crow + i * 16 + v) * ldc + col] = f2bf(x);
            }
        }
    }
}

// ---------------------------------------------------------------------------
// Gate: softmax(combined @ gate_w + gate_b) over E=8. One block per row.
// ---------------------------------------------------------------------------
__global__ __launch_bounds__(256) void gate_kernel(const __bf16* __restrict__ comb,
                                                   const float* __restrict__ gw,
                                                   const float* __restrict__ gb,
                                                   float* __restrict__ gate) {
    const int b = blockIdx.x, tid = threadIdx.x;
    const int lane = tid & 63, wv = tid >> 6;
    const __bf16* row = comb + (size_t)b * 2048;
    float a[8] = {0, 0, 0, 0, 0, 0, 0, 0};
    for (int k = tid; k < 2048; k += 256) {
        const float c = bf2f(row[k]);
        const float4* g4 = (const float4*)(gw + (size_t)k * 8);
        const float4 x = g4[0], y = g4[1];
        a[0] += c * x.x; a[1] += c * x.y; a[2] += c * x.z; a[3] += c * x.w;
        a[4] += c * y.x; a[5] += c * y.y; a[6] += c * y.z; a[7] += c * y.w;
    }
#pragma unroll
    for (int j = 0; j < 8; ++j)
        for (int off = 32; off; off >>= 1) a[j] += __shfl_down(a[j], off, 64);
    __shared__ float red[4][8];
    if (lane == 0) {
#pragma unroll
        for (int j = 0; j < 8; ++j) red[wv][j] = a[j];
    }
    __syncthreads();
    if (tid == 0) {
        float l[8];
        float m = -1e30f;
        for (int j = 0; j < 8; ++j) {
            l[j] = red[0][j] + red[1][j] + red[2][j] + red[3][j] + gb[j];
            m = fmaxf(m, l[j]);
        }
        float s = 0.f;
        for (int j = 0; j < 8; ++j) { l[j] = expf(l[j] - m); s += l[j]; }
        const float inv = 1.0f / s;
        for (int j = 0; j < 8; ++j) gate[(size_t)b * 8 + j] = l[j] * inv;
    }
}

// ---------------------------------------------------------------------------
// Fused LayerNorm + gated expert reduction. One block per row b.
// h2: bf16 [Eg][8192][1024] (group base), gate fp32 [8192][8], ln params [8][1024].
// out fp32 [8192][1024]; accum selects init vs add (for multi-group passes).
// ---------------------------------------------------------------------------
__global__ __launch_bounds__(256) void ln_out_kernel(const __bf16* __restrict__ h2,
                                                     const float* __restrict__ gate,
                                                     const float* __restrict__ lng,
                                                     const float* __restrict__ lnb,
                                                     float* __restrict__ out,
                                                     int Eg, int g0, int accum) {
    const int b = blockIdx.x;
    const int tid = threadIdx.x;
    const int lane = tid & 63, wv = tid >> 6;
    const int d0 = tid * 4;
    __shared__ float sS[4], sSS[4];
    float* orow = out + (size_t)b * 1024 + d0;
    float o0, o1, o2, o3;
    if (accum) {
        const float4 p = *(const float4*)orow;
        o0 = p.x; o1 = p.y; o2 = p.z; o3 = p.w;
    } else {
        o0 = o1 = o2 = o3 = 0.f;
    }
    for (int e = 0; e < Eg; ++e) {
        const __bf16* hp = h2 + ((size_t)e * 8192 + b) * 1024 + d0;
        const bf16x4_t hv = *(const bf16x4_t*)hp;
        const float v0 = bf2f(hv[0]), v1 = bf2f(hv[1]), v2 = bf2f(hv[2]), v3 = bf2f(hv[3]);
        float s = v0 + v1 + v2 + v3;
        float ss = v0 * v0 + v1 * v1 + v2 * v2 + v3 * v3;
        for (int off = 32; off; off >>= 1) {
            s += __shfl_down(s, off, 64);
            ss += __shfl_down(ss, off, 64);
        }
        if (lane == 0) { sS[wv] = s; sSS[wv] = ss; }
        __syncthreads();
        const float S = sS[0] + sS[1] + sS[2] + sS[3];
        const float SS = sSS[0] + sSS[1] + sSS[2] + sSS[3];
        __syncthreads();
        const float mu = S * (1.0f / 1024.0f);
        const float var = SS * (1.0f / 1024.0f) - mu * mu;
        const float rstd = rsqrtf(var + 1e-5f);
        const float w = gate[(size_t)b * 8 + g0 + e];
        const float4 gg = *(const float4*)(lng + (size_t)(g0 + e) * 1024 + d0);
        const float4 bb = *(const float4*)(lnb + (size_t)(g0 + e) * 1024 + d0);
        o0 += w * ((v0 - mu) * rstd * gg.x + bb.x);
        o1 += w * ((v1 - mu) * rstd * gg.y + bb.y);
        o2 += w * ((v2 - mu) * rstd * gg.z + bb.z);
        o3 += w * ((v3 - mu) * rstd * gg.w + bb.w);
    }
    *(float4*)orow = make_float4(o0, o1, o2, o3);
}

// ---------------------------------------------------------------------------
extern "C" void kernel_launch(void* const* d_in, const int* in_sizes, int n_in,
                              void* d_out, int out_size, void* d_ws, size_t ws_size,
                              hipStream_t stream) {
    (void)in_sizes; (void)n_in; (void)out_size;
    const float* visual = (const float*)d_in[0];
    const float* text   = (const float*)d_in[1];
    const float* vis_w  = (const float*)d_in[2];
    const float* vis_b  = (const float*)d_in[3];
    const float* txt_w  = (const float*)d_in[4];
    const float* txt_b  = (const float*)d_in[5];
    const float* gate_w = (const float*)d_in[6];
    const float* gate_b = (const float*)d_in[7];
    const float* w1     = (const float*)d_in[8];
    const float* b1     = (const float*)d_in[9];
    const float* w2     = (const float*)d_in[10];
    const float* b2     = (const float*)d_in[11];
    const float* ln_g   = (const float*)d_in[12];
    const float* ln_b   = (const float*)d_in[13];
    float* out = (float*)d_out;

    const size_t B = 8192, DV = 768, D = 1024, G = 2048, E = 8;

    char* ws = (char*)d_ws;
    size_t o = 0;
    auto alloc = [&](size_t bytes) { size_t r = o; o = (o + bytes + 255) & ~(size_t)255; return r; };
    const size_t off_viswt = alloc(DV * D * 2);
    const size_t off_txtwt = alloc(DV * D * 2);
    const size_t off_w1t   = alloc(E * G * D * 2);
    const size_t off_w2t   = alloc(E * D * D * 2);
    const size_t off_comb  = alloc(B * G * 2);
    const size_t off_gate  = alloc(B * E * 4);
    const size_t fixedEnd = o;
    const size_t inpBytes = 2 * B * DV * 2;  // bf16 visual+text, aliased under h1 region

    int Eg = 1;
    {
        const int cand[4] = {8, 4, 2, 1};
        for (int c = 0; c < 4; ++c) {
            size_t h = (size_t)cand[c] * B * D * 2;
            size_t r1 = h > inpBytes ? h : inpBytes;
            r1 = (r1 + 255) & ~(size_t)255;
            const size_t need = fixedEnd + r1 + h;
            if (need <= ws_size || cand[c] == 1) { Eg = cand[c]; break; }
        }
    }
    const size_t h1bytes = (size_t)Eg * B * D * 2;
    size_t r1sz = h1bytes > inpBytes ? h1bytes : inpBytes;
    r1sz = (r1sz + 255) & ~(size_t)255;
    const size_t off_r1 = fixedEnd;
    const size_t off_h2 = off_r1 + r1sz;

    __bf16* viswt = (__bf16*)(ws + off_viswt);
    __bf16* txtwt = (__bf16*)(ws + off_txtwt);
    __bf16* w1t   = (__bf16*)(ws + off_w1t);
    __bf16* w2t   = (__bf16*)(ws + off_w2t);
    __bf16* comb  = (__bf16*)(ws + off_comb);
    float*  gate  = (float*)(ws + off_gate);
    __bf16* vis_bf = (__bf16*)(ws + off_r1);
    __bf16* txt_bf = vis_bf + B * DV;
    __bf16* h1    = (__bf16*)(ws + off_r1);   // aliases inputs (dead after proj GEMMs)
    __bf16* h2    = (__bf16*)(ws + off_h2);

    // 1) weight transpose+cast to bf16 [N][K]
    transpose_cast<<<dim3(DV / 64, D / 64, 1), 256, 0, stream>>>(vis_w, viswt, (int)DV, (int)D, 0, 0);
    transpose_cast<<<dim3(DV / 64, D / 64, 1), 256, 0, stream>>>(txt_w, txtwt, (int)DV, (int)D, 0, 0);
    transpose_cast<<<dim3(G / 64, D / 64, E), 256, 0, stream>>>(w1, w1t, (int)G, (int)D, G * D, G * D);
    transpose_cast<<<dim3(D / 64, D / 64, E), 256, 0, stream>>>(w2, w2t, (int)D, (int)D, D * D, D * D);

    // 2) activation cast to bf16
    const int n8 = (int)(B * DV / 8);
    cast_kernel<<<(n8 + 255) / 256, 256, 0, stream>>>(visual, vis_bf, n8);
    cast_kernel<<<(n8 + 255) / 256, 256, 0, stream>>>(text, txt_bf, n8);

    // 3) projections -> combined bf16 [B][2048] (vis cols 0..1023, txt cols 1024..2047)
    gemm_bt<0><<<dim3(B / BM, D / BN, 1), 256, 0, stream>>>(vis_bf, (int)DV, 0, viswt, (int)DV, 0,
                                                            vis_b, 0, comb, (int)G, 0, (int)DV);
    gemm_bt<0><<<dim3(B / BM, D / BN, 1), 256, 0, stream>>>(txt_bf, (int)DV, 0, txtwt, (int)DV, 0,
                                                            txt_b, 0, comb + D, (int)G, 0, (int)DV);

    // 4) gate softmax
    gate_kernel<<<(int)B, 256, 0, stream>>>(comb, gate_w, gate_b, gate);

    // 5) experts in groups of Eg
    const int ng = 8 / Eg;
    for (int g = 0; g < ng; ++g) {
        const int g0 = g * Eg;
        gemm_bt<1><<<dim3(B / BM, D / BN, Eg), 256, 0, stream>>>(
            comb, (int)G, 0, w1t + (size_t)g0 * G * D, (int)G, G * D,
            b1 + (size_t)g0 * D, D, h1, (int)D, B * D, (int)G);
        gemm_bt<0><<<dim3(B / BM, D / BN, Eg), 256, 0, stream>>>(
            h1, (int)D, B * D, w2t + (size_t)g0 * D * D, (int)D, D * D,
            b2 + (size_t)g0 * D, D, h2, (int)D, B * D, (int)D);
        ln_out_kernel<<<(int)B, 256, 0, stream>>>(h2, gate, ln_g, ln_b, out, Eg, g0, g > 0 ? 1 : 0);
    }
}

// Round 2
// 890.471 us; speedup vs baseline: 1.0568x; 1.0568x over previous
//
#include <hip/hip_runtime.h>
#include <hip/hip_bf16.h>
#include <math.h>

#define BM 128
#define BN 128
#define BK 32

typedef __bf16 bf16x8_t __attribute__((ext_vector_type(8)));
typedef __bf16 bf16x4_t __attribute__((ext_vector_type(4)));
typedef float f32x4_t __attribute__((ext_vector_type(4)));
typedef float f32x16_t __attribute__((ext_vector_type(16)));

static __device__ __forceinline__ float bf2f(__bf16 b) {
    unsigned short s = __builtin_bit_cast(unsigned short, b);
    unsigned int u = ((unsigned int)s) << 16;
    return __builtin_bit_cast(float, u);
}
static __device__ __forceinline__ __bf16 f2bf(float f) {
    unsigned int u = __builtin_bit_cast(unsigned int, f);
    unsigned int r = (u + 0x7fffu + ((u >> 16) & 1u)) >> 16;
    return __builtin_bit_cast(__bf16, (unsigned short)r);
}
// GELU tanh-form: x * sigmoid(2*s), s = 0.79788456*(x + 0.044715 x^3).
// |err vs exact erf-GELU| <= ~1e-3, far under the 4e-2 tolerance.
static __device__ __forceinline__ float gelu_fast(float x) {
    const float s = x * (0.7978845608f + 0.0356774081f * x * x);
    const float e = __expf(-2.0f * s);
    return x * __builtin_amdgcn_rcpf(1.0f + e);
}

#define GLDS16(gp, lp)                                                                   \
    __builtin_amdgcn_global_load_lds((const __attribute__((address_space(1))) void*)(gp), \
                                     (__attribute__((address_space(3))) void*)(lp), 16, 0, 0)

// ---------------------------------------------------------------------------
// Transpose+cast: in fp32 [K][N] row-major -> out bf16 [N][K] row-major.
// ---------------------------------------------------------------------------
__global__ __launch_bounds__(256) void transpose_cast(const float* __restrict__ in,
                                                      __bf16* __restrict__ out,
                                                      int K, int N,
                                                      size_t inStride, size_t outStride) {
    in += (size_t)blockIdx.z * inStride;
    out += (size_t)blockIdx.z * outStride;
    __shared__ float tile[64][65];
    const int k0 = blockIdx.x * 64, n0 = blockIdx.y * 64;
    const int tid = threadIdx.x;
    const int r = tid >> 4, c4 = (tid & 15) * 4;
#pragma unroll
    for (int p = 0; p < 4; ++p) {
        const float4 v = *(const float4*)&in[(size_t)(k0 + r + p * 16) * N + n0 + c4];
        tile[r + p * 16][c4 + 0] = v.x;
        tile[r + p * 16][c4 + 1] = v.y;
        tile[r + p * 16][c4 + 2] = v.z;
        tile[r + p * 16][c4 + 3] = v.w;
    }
    __syncthreads();
    const int n = tid >> 2, kc = (tid & 3) * 16;
    bf16x8_t t0, t1;
#pragma unroll
    for (int j = 0; j < 8; ++j) t0[j] = f2bf(tile[kc + j][n]);
#pragma unroll
    for (int j = 0; j < 8; ++j) t1[j] = f2bf(tile[kc + 8 + j][n]);
    __bf16* op = &out[(size_t)(n0 + n) * K + k0 + kc];
    *(bf16x8_t*)op = t0;
    *(bf16x8_t*)(op + 8) = t1;
}

// ---------------------------------------------------------------------------
// Plain cast fp32 -> bf16, 8 elements/thread.
// ---------------------------------------------------------------------------
__global__ __launch_bounds__(256) void cast_kernel(const float* __restrict__ in,
                                                   __bf16* __restrict__ out, int n8) {
    const int i = blockIdx.x * 256 + threadIdx.x;
    if (i < n8) {
        const float4* p = (const float4*)(in + (size_t)i * 8);
        const float4 a = p[0], b = p[1];
        bf16x8_t v;
        v[0] = f2bf(a.x); v[1] = f2bf(a.y); v[2] = f2bf(a.z); v[3] = f2bf(a.w);
        v[4] = f2bf(b.x); v[5] = f2bf(b.y); v[6] = f2bf(b.z); v[7] = f2bf(b.w);
        *(bf16x8_t*)(out + (size_t)i * 8) = v;
    }
}

// ---------------------------------------------------------------------------
// bf16 GEMM: C[M,N] = act(A[M,K] @ B^T[N,K] + bias), C bf16.
// 128x128 tile, BK=32, 256 threads, 2x2 waves, each wave 64x64 via 2x2
// mfma_f32_32x32x16_bf16 frags. LDS uses XOR swizzle on the 16B chunk index
// (c = g ^ ((row>>1)&3)) to spread fragment ds_read_b128 across bank groups;
// the swizzle is applied on the GLOBAL side of global_load_lds (LDS dest stays
// lane-contiguous as required).
// ---------------------------------------------------------------------------
template <int ACT>
__global__ __launch_bounds__(256) void gemm_bt(const __bf16* __restrict__ Ab, int lda, size_t strideAe,
                                               const __bf16* __restrict__ Bb, int ldb, size_t strideBe,
                                               const float* __restrict__ biasb, size_t strideBiasE,
                                               __bf16* __restrict__ Cb, int ldc, size_t strideCe,
                                               int K) {
    __shared__ __bf16 As[BM * BK];
    __shared__ __bf16 Bs[BN * BK];

    const __bf16* A = Ab + (size_t)blockIdx.z * strideAe;
    const __bf16* Bt = Bb + (size_t)blockIdx.z * strideBe;
    const float* bias = biasb + (size_t)blockIdx.z * strideBiasE;
    __bf16* C = Cb + (size_t)blockIdx.z * strideCe;

    const int tid = threadIdx.x;
    const int bm = blockIdx.x, bn = blockIdx.y;
    const int lane = tid & 63, wave = tid >> 6;
    const int wm = wave >> 1, wn = wave & 1;
    const int l = lane & 31, hi = lane >> 5;

    // staging: slot tid -> LDS row tid>>2, chunk tid&3 (contiguous, lane*16B).
    // That LDS slot must hold global chunk g with (g ^ swz(row)) == tid&3.
    const int srow = tid >> 2;
    const int schunk = (tid & 3) ^ ((tid >> 3) & 3);
    const __bf16* ag = A + (size_t)(bm * BM + srow) * lda + schunk * 8;
    const __bf16* bg = Bt + (size_t)(bn * BN + srow) * ldb + schunk * 8;
    __bf16* asl = As + tid * 8;
    __bf16* bsl = Bs + tid * 8;

    // fragment read pointers: row = w*64 + mi*32 + l, chunk = (kstep*2+hi) ^ ((l>>1)&3)
    const int swz = (l >> 1) & 3;
    const int c0 = hi ^ swz;  // kstep 0; kstep 1 chunk = c0 ^ 2
    const __bf16* afp0 = As + (size_t)(wm * 64 + l) * BK + c0 * 8;
    const __bf16* afp1 = As + (size_t)(wm * 64 + l) * BK + (c0 ^ 2) * 8;
    const __bf16* bfp0 = Bs + (size_t)(wn * 64 + l) * BK + c0 * 8;
    const __bf16* bfp1 = Bs + (size_t)(wn * 64 + l) * BK + (c0 ^ 2) * 8;

    f32x16_t acc[2][2] = {};

    const int nk = K / BK;
    for (int kt = 0; kt < nk; ++kt) {
        GLDS16(ag, asl);
        GLDS16(ag + (size_t)64 * lda, asl + 256 * 8);
        GLDS16(bg, bsl);
        GLDS16(bg + (size_t)64 * ldb, bsl + 256 * 8);
        ag += BK;
        bg += BK;
        __syncthreads();
        // kstep 0
        {
            const bf16x8_t a0 = *(const bf16x8_t*)afp0;
            const bf16x8_t a1 = *(const bf16x8_t*)(afp0 + 32 * BK);
            const bf16x8_t b0 = *(const bf16x8_t*)bfp0;
            const bf16x8_t b1 = *(const bf16x8_t*)(bfp0 + 32 * BK);
            acc[0][0] = __builtin_amdgcn_mfma_f32_32x32x16_bf16(a0, b0, acc[0][0], 0, 0, 0);
            acc[0][1] = __builtin_amdgcn_mfma_f32_32x32x16_bf16(a0, b1, acc[0][1], 0, 0, 0);
            acc[1][0] = __builtin_amdgcn_mfma_f32_32x32x16_bf16(a1, b0, acc[1][0], 0, 0, 0);
            acc[1][1] = __builtin_amdgcn_mfma_f32_32x32x16_bf16(a1, b1, acc[1][1], 0, 0, 0);
        }
        // kstep 1
        {
            const bf16x8_t a0 = *(const bf16x8_t*)afp1;
            const bf16x8_t a1 = *(const bf16x8_t*)(afp1 + 32 * BK);
            const bf16x8_t b0 = *(const bf16x8_t*)bfp1;
            const bf16x8_t b1 = *(const bf16x8_t*)(bfp1 + 32 * BK);
            acc[0][0] = __builtin_amdgcn_mfma_f32_32x32x16_bf16(a0, b0, acc[0][0], 0, 0, 0);
            acc[0][1] = __builtin_amdgcn_mfma_f32_32x32x16_bf16(a0, b1, acc[0][1], 0, 0, 0);
            acc[1][0] = __builtin_amdgcn_mfma_f32_32x32x16_bf16(a1, b0, acc[1][0], 0, 0, 0);
            acc[1][1] = __builtin_amdgcn_mfma_f32_32x32x16_bf16(a1, b1, acc[1][1], 0, 0, 0);
        }
        __syncthreads();
    }

    // epilogue: 32x32 C/D layout: col = lane&31, row = (reg&3) + 8*(reg>>2) + 4*hi
    const int colbase = bn * BN + wn * 64 + l;
    const int rowbase = bm * BM + wm * 64 + 4 * hi;
#pragma unroll
    for (int ni = 0; ni < 2; ++ni) {
        const int col = colbase + ni * 32;
        const float bv = bias[col];
#pragma unroll
        for (int mi = 0; mi < 2; ++mi) {
#pragma unroll
            for (int v = 0; v < 16; ++v) {
                const int row = rowbase + mi * 32 + (v & 3) + 8 * (v >> 2);
                float x = acc[mi][ni][v] + bv;
                if (ACT == 1) x = gelu_fast(x);
                C[(size_t)row * ldc + col] = f2bf(x);
            }
        }
    }
}

// ---------------------------------------------------------------------------
// Gate: softmax(combined @ gate_w + gate_b) over E=8. One block per row.
// ---------------------------------------------------------------------------
__global__ __launch_bounds__(256) void gate_kernel(const __bf16* __restrict__ comb,
                                                   const float* __restrict__ gw,
                                                   const float* __restrict__ gb,
                                                   float* __restrict__ gate) {
    const int b = blockIdx.x, tid = threadIdx.x;
    const int lane = tid & 63, wv = tid >> 6;
    const __bf16* row = comb + (size_t)b * 2048;
    float a[8] = {0, 0, 0, 0, 0, 0, 0, 0};
    for (int k = tid; k < 2048; k += 256) {
        const float c = bf2f(row[k]);
        const float4* g4 = (const float4*)(gw + (size_t)k * 8);
        const float4 x = g4[0], y = g4[1];
        a[0] += c * x.x; a[1] += c * x.y; a[2] += c * x.z; a[3] += c * x.w;
        a[4] += c * y.x; a[5] += c * y.y; a[6] += c * y.z; a[7] += c * y.w;
    }
#pragma unroll
    for (int j = 0; j < 8; ++j)
        for (int off = 32; off; off >>= 1) a[j] += __shfl_down(a[j], off, 64);
    __shared__ float red[4][8];
    if (lane == 0) {
#pragma unroll
        for (int j = 0; j < 8; ++j) red[wv][j] = a[j];
    }
    __syncthreads();
    if (tid == 0) {
        float l[8];
        float m = -1e30f;
        for (int j = 0; j < 8; ++j) {
            l[j] = red[0][j] + red[1][j] + red[2][j] + red[3][j] + gb[j];
            m = fmaxf(m, l[j]);
        }
        float s = 0.f;
        for (int j = 0; j < 8; ++j) { l[j] = expf(l[j] - m); s += l[j]; }
        const float inv = 1.0f / s;
        for (int j = 0; j < 8; ++j) gate[(size_t)b * 8 + j] = l[j] * inv;
    }
}

// ---------------------------------------------------------------------------
// Fused LayerNorm + gated expert reduction. One block per row b.
// ---------------------------------------------------------------------------
__global__ __launch_bounds__(256) void ln_out_kernel(const __bf16* __restrict__ h2,
                                                     const float* __restrict__ gate,
                                                     const float* __restrict__ lng,
                                                     const float* __restrict__ lnb,
                                                     float* __restrict__ out,
                                                     int Eg, int g0, int accum) {
    const int b = blockIdx.x;
    const int tid = threadIdx.x;
    const int lane = tid & 63, wv = tid >> 6;
    const int d0 = tid * 4;
    __shared__ float sS[4], sSS[4];
    float* orow = out + (size_t)b * 1024 + d0;
    float o0, o1, o2, o3;
    if (accum) {
        const float4 p = *(const float4*)orow;
        o0 = p.x; o1 = p.y; o2 = p.z; o3 = p.w;
    } else {
        o0 = o1 = o2 = o3 = 0.f;
    }
    for (int e = 0; e < Eg; ++e) {
        const __bf16* hp = h2 + ((size_t)e * 8192 + b) * 1024 + d0;
        const bf16x4_t hv = *(const bf16x4_t*)hp;
        const float v0 = bf2f(hv[0]), v1 = bf2f(hv[1]), v2 = bf2f(hv[2]), v3 = bf2f(hv[3]);
        float s = v0 + v1 + v2 + v3;
        float ss = v0 * v0 + v1 * v1 + v2 * v2 + v3 * v3;
        for (int off = 32; off; off >>= 1) {
            s += __shfl_down(s, off, 64);
            ss += __shfl_down(ss, off, 64);
        }
        if (lane == 0) { sS[wv] = s; sSS[wv] = ss; }
        __syncthreads();
        const float S = sS[0] + sS[1] + sS[2] + sS[3];
        const float SS = sSS[0] + sSS[1] + sSS[2] + sSS[3];
        __syncthreads();
        const float mu = S * (1.0f / 1024.0f);
        const float var = SS * (1.0f / 1024.0f) - mu * mu;
        const float rstd = rsqrtf(var + 1e-5f);
        const float w = gate[(size_t)b * 8 + g0 + e];
        const float4 gg = *(const float4*)(lng + (size_t)(g0 + e) * 1024 + d0);
        const float4 bb = *(const float4*)(lnb + (size_t)(g0 + e) * 1024 + d0);
        o0 += w * ((v0 - mu) * rstd * gg.x + bb.x);
        o1 += w * ((v1 - mu) * rstd * gg.y + bb.y);
        o2 += w * ((v2 - mu) * rstd * gg.z + bb.z);
        o3 += w * ((v3 - mu) * rstd * gg.w + bb.w);
    }
    *(float4*)orow = make_float4(o0, o1, o2, o3);
}

// ---------------------------------------------------------------------------
extern "C" void kernel_launch(void* const* d_in, const int* in_sizes, int n_in,
                              void* d_out, int out_size, void* d_ws, size_t ws_size,
                              hipStream_t stream) {
    (void)in_sizes; (void)n_in; (void)out_size;
    const float* visual = (const float*)d_in[0];
    const float* text   = (const float*)d_in[1];
    const float* vis_w  = (const float*)d_in[2];
    const float* vis_b  = (const float*)d_in[3];
    const float* txt_w  = (const float*)d_in[4];
    const float* txt_b  = (const float*)d_in[5];
    const float* gate_w = (const float*)d_in[6];
    const float* gate_b = (const float*)d_in[7];
    const float* w1     = (const float*)d_in[8];
    const float* b1     = (const float*)d_in[9];
    const float* w2     = (const float*)d_in[10];
    const float* b2     = (const float*)d_in[11];
    const float* ln_g   = (const float*)d_in[12];
    const float* ln_b   = (const float*)d_in[13];
    float* out = (float*)d_out;

    const size_t B = 8192, DV = 768, D = 1024, G = 2048, E = 8;

    char* ws = (char*)d_ws;
    size_t o = 0;
    auto alloc = [&](size_t bytes) { size_t r = o; o = (o + bytes + 255) & ~(size_t)255; return r; };
    const size_t off_viswt = alloc(DV * D * 2);
    const size_t off_txtwt = alloc(DV * D * 2);
    const size_t off_w1t   = alloc(E * G * D * 2);
    const size_t off_w2t   = alloc(E * D * D * 2);
    const size_t off_comb  = alloc(B * G * 2);
    const size_t off_gate  = alloc(B * E * 4);
    const size_t fixedEnd = o;
    const size_t inpBytes = 2 * B * DV * 2;  // bf16 visual+text, aliased under h1 region

    int Eg = 1;
    {
        const int cand[4] = {8, 4, 2, 1};
        for (int c = 0; c < 4; ++c) {
            size_t h = (size_t)cand[c] * B * D * 2;
            size_t r1 = h > inpBytes ? h : inpBytes;
            r1 = (r1 + 255) & ~(size_t)255;
            const size_t need = fixedEnd + r1 + h;
            if (need <= ws_size || cand[c] == 1) { Eg = cand[c]; break; }
        }
    }
    const size_t h1bytes = (size_t)Eg * B * D * 2;
    size_t r1sz = h1bytes > inpBytes ? h1bytes : inpBytes;
    r1sz = (r1sz + 255) & ~(size_t)255;
    const size_t off_r1 = fixedEnd;
    const size_t off_h2 = off_r1 + r1sz;

    __bf16* viswt = (__bf16*)(ws + off_viswt);
    __bf16* txtwt = (__bf16*)(ws + off_txtwt);
    __bf16* w1t   = (__bf16*)(ws + off_w1t);
    __bf16* w2t   = (__bf16*)(ws + off_w2t);
    __bf16* comb  = (__bf16*)(ws + off_comb);
    float*  gate  = (float*)(ws + off_gate);
    __bf16* vis_bf = (__bf16*)(ws + off_r1);
    __bf16* txt_bf = vis_bf + B * DV;
    __bf16* h1    = (__bf16*)(ws + off_r1);   // aliases bf16 inputs (dead after proj GEMMs)
    __bf16* h2    = (__bf16*)(ws + off_h2);

    // 1) weight transpose+cast to bf16 [N][K]
    transpose_cast<<<dim3(DV / 64, D / 64, 1), 256, 0, stream>>>(vis_w, viswt, (int)DV, (int)D, 0, 0);
    transpose_cast<<<dim3(DV / 64, D / 64, 1), 256, 0, stream>>>(txt_w, txtwt, (int)DV, (int)D, 0, 0);
    transpose_cast<<<dim3(G / 64, D / 64, E), 256, 0, stream>>>(w1, w1t, (int)G, (int)D, G * D, G * D);
    transpose_cast<<<dim3(D / 64, D / 64, E), 256, 0, stream>>>(w2, w2t, (int)D, (int)D, D * D, D * D);

    // 2) activation cast to bf16
    const int n8 = (int)(B * DV / 8);
    cast_kernel<<<(n8 + 255) / 256, 256, 0, stream>>>(visual, vis_bf, n8);
    cast_kernel<<<(n8 + 255) / 256, 256, 0, stream>>>(text, txt_bf, n8);

    // 3) projections -> combined bf16 [B][2048]
    gemm_bt<0><<<dim3(B / BM, D / BN, 1), 256, 0, stream>>>(vis_bf, (int)DV, 0, viswt, (int)DV, 0,
                                                            vis_b, 0, comb, (int)G, 0, (int)DV);
    gemm_bt<0><<<dim3(B / BM, D / BN, 1), 256, 0, stream>>>(txt_bf, (int)DV, 0, txtwt, (int)DV, 0,
                                                            txt_b, 0, comb + D, (int)G, 0, (int)DV);

    // 4) gate softmax
    gate_kernel<<<(int)B, 256, 0, stream>>>(comb, gate_w, gate_b, gate);

    // 5) experts in groups of Eg
    const int ng = 8 / Eg;
    for (int g = 0; g < ng; ++g) {
        const int g0 = g * Eg;
        gemm_bt<1><<<dim3(B / BM, D / BN, Eg), 256, 0, stream>>>(
            comb, (int)G, 0, w1t + (size_t)g0 * G * D, (int)G, G * D,
            b1 + (size_t)g0 * D, D, h1, (int)D, B * D, (int)G);
        gemm_bt<0><<<dim3(B / BM, D / BN, Eg), 256, 0, stream>>>(
            h1, (int)D, B * D, w2t + (size_t)g0 * D * D, (int)D, D * D,
            b2 + (size_t)g0 * D, D, h2, (int)D, B * D, (int)D);
        ln_out_kernel<<<(int)B, 256, 0, stream>>>(h2, gate, ln_g, ln_b, out, Eg, g0, g > 0 ? 1 : 0);
    }
}

// Round 3
// 829.069 us; speedup vs baseline: 1.1351x; 1.0741x over previous
//
#include <hip/hip_runtime.h>
#include <hip/hip_bf16.h>
#include <math.h>

#define BM 128
#define BN 128
#define BK 64

typedef __bf16 bf16x8_t __attribute__((ext_vector_type(8)));
typedef __bf16 bf16x4_t __attribute__((ext_vector_type(4)));
typedef float f32x16_t __attribute__((ext_vector_type(16)));

static __device__ __forceinline__ float bf2f(__bf16 b) {
    unsigned short s = __builtin_bit_cast(unsigned short, b);
    unsigned int u = ((unsigned int)s) << 16;
    return __builtin_bit_cast(float, u);
}
static __device__ __forceinline__ __bf16 f2bf(float f) {
    unsigned int u = __builtin_bit_cast(unsigned int, f);
    unsigned int r = (u + 0x7fffu + ((u >> 16) & 1u)) >> 16;
    return __builtin_bit_cast(__bf16, (unsigned short)r);
}
// GELU tanh-form, |err vs exact| ~1e-3 << 4e-2 tolerance.
static __device__ __forceinline__ float gelu_fast(float x) {
    const float s = x * (0.7978845608f + 0.0356774081f * x * x);
    const float e = __expf(-2.0f * s);
    return x * __builtin_amdgcn_rcpf(1.0f + e);
}

#define GLDS16(gp, lp)                                                                   \
    __builtin_amdgcn_global_load_lds((const __attribute__((address_space(1))) void*)(gp), \
                                     (__attribute__((address_space(3))) void*)(lp), 16, 0, 0)

// ---------------------------------------------------------------------------
// frag_cast: fp32 W[K][N] -> bf16 B'[K/8][N][8], B'[c][n][j] = W[c*8+j][n].
// B-fragments of mfma_32x32x16_bf16 (lane n=l, k=hi*8+j) then load as one
// coalesced bf16x8 per lane. 64x64 tiles, 256 threads, grid.z via strides.
// ---------------------------------------------------------------------------
__global__ __launch_bounds__(256) void frag_cast(const float* __restrict__ in,
                                                 __bf16* __restrict__ out,
                                                 int K, int N,
                                                 size_t inStride, size_t outStride) {
    in += (size_t)blockIdx.z * inStride;
    out += (size_t)blockIdx.z * outStride;
    __shared__ float tile[64][65];
    const int k0 = blockIdx.x * 64, n0 = blockIdx.y * 64;
    const int tid = threadIdx.x;
    const int r = tid >> 4, c4 = (tid & 15) * 4;
#pragma unroll
    for (int p = 0; p < 4; ++p) {
        const float4 v = *(const float4*)&in[(size_t)(k0 + r + p * 16) * N + n0 + c4];
        tile[r + p * 16][c4 + 0] = v.x;
        tile[r + p * 16][c4 + 1] = v.y;
        tile[r + p * 16][c4 + 2] = v.z;
        tile[r + p * 16][c4 + 3] = v.w;
    }
    __syncthreads();
    const int c = tid >> 5, nn0 = (tid & 31) * 2;
#pragma unroll
    for (int t = 0; t < 2; ++t) {
        const int nn = nn0 + t;
        bf16x8_t v;
#pragma unroll
        for (int j = 0; j < 8; ++j) v[j] = f2bf(tile[c * 8 + j][nn]);
        *(bf16x8_t*)&out[((size_t)(k0 >> 3) + c) * N * 8 + (size_t)(n0 + nn) * 8] = v;
    }
}

// ---------------------------------------------------------------------------
// Plain cast fp32 -> bf16, 8 elements/thread.
// ---------------------------------------------------------------------------
__global__ __launch_bounds__(256) void cast_kernel(const float* __restrict__ in,
                                                   __bf16* __restrict__ out, int n8) {
    const int i = blockIdx.x * 256 + threadIdx.x;
    if (i < n8) {
        const float4* p = (const float4*)(in + (size_t)i * 8);
        const float4 a = p[0], b = p[1];
        bf16x8_t v;
        v[0] = f2bf(a.x); v[1] = f2bf(a.y); v[2] = f2bf(a.z); v[3] = f2bf(a.w);
        v[4] = f2bf(b.x); v[5] = f2bf(b.y); v[6] = f2bf(b.z); v[7] = f2bf(b.w);
        *(bf16x8_t*)(out + (size_t)i * 8) = v;
    }
}

// ---------------------------------------------------------------------------
// bf16 GEMM: C[M,N] = act(A[M,K] @ W + bias), A row-major via LDS (GLDS16,
// XOR-swizzled chunks), W pre-packed frag-native B'[K/8][N][8] read directly
// from global into VGPRs (no LDS for B). 128x128 tile, BK=64, 256 threads,
// 2x2 waves x (2x2 mfma_f32_32x32x16_bf16). ACT: 0=none, 1=GELU.
// ---------------------------------------------------------------------------
template <int ACT>
__global__ __launch_bounds__(256) void gemm_bt(const __bf16* __restrict__ Ab, int lda, size_t strideAe,
                                               const __bf16* __restrict__ Bb, int Bn, size_t strideBe,
                                               const float* __restrict__ biasb, size_t strideBiasE,
                                               __bf16* __restrict__ Cb, int ldc, size_t strideCe,
                                               int K) {
    __shared__ __bf16 As[BM * BK];  // 16 KB

    const __bf16* A = Ab + (size_t)blockIdx.z * strideAe;
    const __bf16* Bt = Bb + (size_t)blockIdx.z * strideBe;
    const float* bias = biasb + (size_t)blockIdx.z * strideBiasE;
    __bf16* C = Cb + (size_t)blockIdx.z * strideCe;

    const int tid = threadIdx.x;
    const int bm = blockIdx.x, bn = blockIdx.y;
    const int lane = tid & 63, wave = tid >> 6;
    const int wm = wave >> 1, wn = wave & 1;
    const int l = lane & 31, hi = lane >> 5;

    // --- A staging: LDS[row][c'] holds global chunk c' ^ (row&7); GLDS dest
    // is lane-contiguous (base + lane*16B) as required.
    const int srow = tid >> 3;                    // 0..31
    const int schunk = (tid & 7) ^ (srow & 7);    // global chunk for this slot
    const __bf16* ag = A + (size_t)(bm * BM + srow) * lda + schunk * 8;
    __bf16* asl = As + tid * 8;

    // --- A fragment read base: row = wm*64 + mi*32 + l, chunk' = (2s+hi)^(l&7)
    const int c0 = hi ^ (l & 7);
    const __bf16* base_a = As + (size_t)(wm * 64 + l) * BK;

    // --- B fragment base: frag(s,ni) at chunk kt*8+2s+hi, col bn*BN+wn*64+ni*32+l
    const size_t Bn8 = (size_t)Bn * 8;
    const __bf16* bbase = Bt + (size_t)hi * Bn8 + (size_t)(bn * BN + wn * 64 + l) * 8;

    f32x16_t acc[2][2] = {};

    const int nk = K / BK;
    for (int kt = 0; kt < nk; ++kt) {
        // B fragments for this K-tile: 8 coalesced global b128 loads
        bf16x8_t bfr[4][2];
        const __bf16* bp = bbase + (size_t)(kt * 8) * Bn8;
#pragma unroll
        for (int s = 0; s < 4; ++s) {
            bfr[s][0] = *(const bf16x8_t*)(bp + (size_t)(2 * s) * Bn8);
            bfr[s][1] = *(const bf16x8_t*)(bp + (size_t)(2 * s) * Bn8 + 256);
        }
        // A tile staging (4 GLDS of 16B/lane)
        GLDS16(ag, asl);
        GLDS16(ag + (size_t)32 * lda, asl + 2048);
        GLDS16(ag + (size_t)64 * lda, asl + 4096);
        GLDS16(ag + (size_t)96 * lda, asl + 6144);
        ag += BK;
        __syncthreads();  // drains GLDS + B loads together
#pragma unroll
        for (int s = 0; s < 4; ++s) {
            const int co = (c0 ^ (2 * s)) * 8;
            const bf16x8_t a0 = *(const bf16x8_t*)(base_a + co);
            const bf16x8_t a1 = *(const bf16x8_t*)(base_a + 2048 + co);
            acc[0][0] = __builtin_amdgcn_mfma_f32_32x32x16_bf16(a0, bfr[s][0], acc[0][0], 0, 0, 0);
            acc[0][1] = __builtin_amdgcn_mfma_f32_32x32x16_bf16(a0, bfr[s][1], acc[0][1], 0, 0, 0);
            acc[1][0] = __builtin_amdgcn_mfma_f32_32x32x16_bf16(a1, bfr[s][0], acc[1][0], 0, 0, 0);
            acc[1][1] = __builtin_amdgcn_mfma_f32_32x32x16_bf16(a1, bfr[s][1], acc[1][1], 0, 0, 0);
        }
        __syncthreads();
    }

    // epilogue: 32x32 C/D layout: col = lane&31, row = (reg&3) + 8*(reg>>2) + 4*hi
    const int colbase = bn * BN + wn * 64 + l;
    const int rowbase = bm * BM + wm * 64 + 4 * hi;
#pragma unroll
    for (int ni = 0; ni < 2; ++ni) {
        const int col = colbase + ni * 32;
        const float bv = bias[col];
#pragma unroll
        for (int mi = 0; mi < 2; ++mi) {
#pragma unroll
            for (int v = 0; v < 16; ++v) {
                const int row = rowbase + mi * 32 + (v & 3) + 8 * (v >> 2);
                float x = acc[mi][ni][v] + bv;
                if (ACT == 1) x = gelu_fast(x);
                C[(size_t)row * ldc + col] = f2bf(x);
            }
        }
    }
}

// ---------------------------------------------------------------------------
// Gate: softmax(combined @ gate_w + gate_b) over E=8. One block per row.
// ---------------------------------------------------------------------------
__global__ __launch_bounds__(256) void gate_kernel(const __bf16* __restrict__ comb,
                                                   const float* __restrict__ gw,
                                                   const float* __restrict__ gb,
                                                   float* __restrict__ gate) {
    const int b = blockIdx.x, tid = threadIdx.x;
    const int lane = tid & 63, wv = tid >> 6;
    const __bf16* row = comb + (size_t)b * 2048;
    float a[8] = {0, 0, 0, 0, 0, 0, 0, 0};
    for (int k = tid; k < 2048; k += 256) {
        const float c = bf2f(row[k]);
        const float4* g4 = (const float4*)(gw + (size_t)k * 8);
        const float4 x = g4[0], y = g4[1];
        a[0] += c * x.x; a[1] += c * x.y; a[2] += c * x.z; a[3] += c * x.w;
        a[4] += c * y.x; a[5] += c * y.y; a[6] += c * y.z; a[7] += c * y.w;
    }
#pragma unroll
    for (int j = 0; j < 8; ++j)
        for (int off = 32; off; off >>= 1) a[j] += __shfl_down(a[j], off, 64);
    __shared__ float red[4][8];
    if (lane == 0) {
#pragma unroll
        for (int j = 0; j < 8; ++j) red[wv][j] = a[j];
    }
    __syncthreads();
    if (tid == 0) {
        float l[8];
        float m = -1e30f;
        for (int j = 0; j < 8; ++j) {
            l[j] = red[0][j] + red[1][j] + red[2][j] + red[3][j] + gb[j];
            m = fmaxf(m, l[j]);
        }
        float s = 0.f;
        for (int j = 0; j < 8; ++j) { l[j] = expf(l[j] - m); s += l[j]; }
        const float inv = 1.0f / s;
        for (int j = 0; j < 8; ++j) gate[(size_t)b * 8 + j] = l[j] * inv;
    }
}

// ---------------------------------------------------------------------------
// Fused LayerNorm + gated expert reduction. One block per row b.
// ---------------------------------------------------------------------------
__global__ __launch_bounds__(256) void ln_out_kernel(const __bf16* __restrict__ h2,
                                                     const float* __restrict__ gate,
                                                     const float* __restrict__ lng,
                                                     const float* __restrict__ lnb,
                                                     float* __restrict__ out,
                                                     int Eg, int g0, int accum) {
    const int b = blockIdx.x;
    const int tid = threadIdx.x;
    const int lane = tid & 63, wv = tid >> 6;
    const int d0 = tid * 4;
    __shared__ float sS[4], sSS[4];
    float* orow = out + (size_t)b * 1024 + d0;
    float o0, o1, o2, o3;
    if (accum) {
        const float4 p = *(const float4*)orow;
        o0 = p.x; o1 = p.y; o2 = p.z; o3 = p.w;
    } else {
        o0 = o1 = o2 = o3 = 0.f;
    }
    for (int e = 0; e < Eg; ++e) {
        const __bf16* hp = h2 + ((size_t)e * 8192 + b) * 1024 + d0;
        const bf16x4_t hv = *(const bf16x4_t*)hp;
        const float v0 = bf2f(hv[0]), v1 = bf2f(hv[1]), v2 = bf2f(hv[2]), v3 = bf2f(hv[3]);
        float s = v0 + v1 + v2 + v3;
        float ss = v0 * v0 + v1 * v1 + v2 * v2 + v3 * v3;
        for (int off = 32; off; off >>= 1) {
            s += __shfl_down(s, off, 64);
            ss += __shfl_down(ss, off, 64);
        }
        if (lane == 0) { sS[wv] = s; sSS[wv] = ss; }
        __syncthreads();
        const float S = sS[0] + sS[1] + sS[2] + sS[3];
        const float SS = sSS[0] + sSS[1] + sSS[2] + sSS[3];
        __syncthreads();
        const float mu = S * (1.0f / 1024.0f);
        const float var = SS * (1.0f / 1024.0f) - mu * mu;
        const float rstd = rsqrtf(var + 1e-5f);
        const float w = gate[(size_t)b * 8 + g0 + e];
        const float4 gg = *(const float4*)(lng + (size_t)(g0 + e) * 1024 + d0);
        const float4 bb = *(const float4*)(lnb + (size_t)(g0 + e) * 1024 + d0);
        o0 += w * ((v0 - mu) * rstd * gg.x + bb.x);
        o1 += w * ((v1 - mu) * rstd * gg.y + bb.y);
        o2 += w * ((v2 - mu) * rstd * gg.z + bb.z);
        o3 += w * ((v3 - mu) * rstd * gg.w + bb.w);
    }
    *(float4*)orow = make_float4(o0, o1, o2, o3);
}

// ---------------------------------------------------------------------------
extern "C" void kernel_launch(void* const* d_in, const int* in_sizes, int n_in,
                              void* d_out, int out_size, void* d_ws, size_t ws_size,
                              hipStream_t stream) {
    (void)in_sizes; (void)n_in; (void)out_size;
    const float* visual = (const float*)d_in[0];
    const float* text   = (const float*)d_in[1];
    const float* vis_w  = (const float*)d_in[2];
    const float* vis_b  = (const float*)d_in[3];
    const float* txt_w  = (const float*)d_in[4];
    const float* txt_b  = (const float*)d_in[5];
    const float* gate_w = (const float*)d_in[6];
    const float* gate_b = (const float*)d_in[7];
    const float* w1     = (const float*)d_in[8];
    const float* b1     = (const float*)d_in[9];
    const float* w2     = (const float*)d_in[10];
    const float* b2     = (const float*)d_in[11];
    const float* ln_g   = (const float*)d_in[12];
    const float* ln_b   = (const float*)d_in[13];
    float* out = (float*)d_out;

    const size_t B = 8192, DV = 768, D = 1024, G = 2048, E = 8;

    char* ws = (char*)d_ws;
    size_t o = 0;
    auto alloc = [&](size_t bytes) { size_t r = o; o = (o + bytes + 255) & ~(size_t)255; return r; };
    const size_t off_viswt = alloc(DV * D * 2);
    const size_t off_txtwt = alloc(DV * D * 2);
    const size_t off_w1t   = alloc(E * G * D * 2);
    const size_t off_w2t   = alloc(E * D * D * 2);
    const size_t off_comb  = alloc(B * G * 2);
    const size_t off_gate  = alloc(B * E * 4);
    const size_t fixedEnd = o;
    const size_t inpBytes = 2 * B * DV * 2;  // bf16 visual+text, aliased under h1 region

    int Eg = 1;
    {
        const int cand[4] = {8, 4, 2, 1};
        for (int c = 0; c < 4; ++c) {
            size_t h = (size_t)cand[c] * B * D * 2;
            size_t r1 = h > inpBytes ? h : inpBytes;
            r1 = (r1 + 255) & ~(size_t)255;
            const size_t need = fixedEnd + r1 + h;
            if (need <= ws_size || cand[c] == 1) { Eg = cand[c]; break; }
        }
    }
    const size_t h1bytes = (size_t)Eg * B * D * 2;
    size_t r1sz = h1bytes > inpBytes ? h1bytes : inpBytes;
    r1sz = (r1sz + 255) & ~(size_t)255;
    const size_t off_r1 = fixedEnd;
    const size_t off_h2 = off_r1 + r1sz;

    __bf16* viswt = (__bf16*)(ws + off_viswt);
    __bf16* txtwt = (__bf16*)(ws + off_txtwt);
    __bf16* w1t   = (__bf16*)(ws + off_w1t);
    __bf16* w2t   = (__bf16*)(ws + off_w2t);
    __bf16* comb  = (__bf16*)(ws + off_comb);
    float*  gate  = (float*)(ws + off_gate);
    __bf16* vis_bf = (__bf16*)(ws + off_r1);
    __bf16* txt_bf = vis_bf + B * DV;
    __bf16* h1    = (__bf16*)(ws + off_r1);   // aliases bf16 inputs (dead after proj GEMMs)
    __bf16* h2    = (__bf16*)(ws + off_h2);

    // 1) weight pack+cast to frag-native bf16 [K/8][N][8]
    frag_cast<<<dim3(DV / 64, D / 64, 1), 256, 0, stream>>>(vis_w, viswt, (int)DV, (int)D, 0, 0);
    frag_cast<<<dim3(DV / 64, D / 64, 1), 256, 0, stream>>>(txt_w, txtwt, (int)DV, (int)D, 0, 0);
    frag_cast<<<dim3(G / 64, D / 64, E), 256, 0, stream>>>(w1, w1t, (int)G, (int)D, G * D, G * D);
    frag_cast<<<dim3(D / 64, D / 64, E), 256, 0, stream>>>(w2, w2t, (int)D, (int)D, D * D, D * D);

    // 2) activation cast to bf16
    const int n8 = (int)(B * DV / 8);
    cast_kernel<<<(n8 + 255) / 256, 256, 0, stream>>>(visual, vis_bf, n8);
    cast_kernel<<<(n8 + 255) / 256, 256, 0, stream>>>(text, txt_bf, n8);

    // 3) projections -> combined bf16 [B][2048]
    gemm_bt<0><<<dim3(B / BM, D / BN, 1), 256, 0, stream>>>(vis_bf, (int)DV, 0, viswt, (int)D, 0,
                                                            vis_b, 0, comb, (int)G, 0, (int)DV);
    gemm_bt<0><<<dim3(B / BM, D / BN, 1), 256, 0, stream>>>(txt_bf, (int)DV, 0, txtwt, (int)D, 0,
                                                            txt_b, 0, comb + D, (int)G, 0, (int)DV);

    // 4) gate softmax
    gate_kernel<<<(int)B, 256, 0, stream>>>(comb, gate_w, gate_b, gate);

    // 5) experts in groups of Eg
    const int ng = 8 / Eg;
    for (int g = 0; g < ng; ++g) {
        const int g0 = g * Eg;
        gemm_bt<1><<<dim3(B / BM, D / BN, Eg), 256, 0, stream>>>(
            comb, (int)G, 0, w1t + (size_t)g0 * G * D, (int)D, G * D,
            b1 + (size_t)g0 * D, D, h1, (int)D, B * D, (int)G);
        gemm_bt<0><<<dim3(B / BM, D / BN, Eg), 256, 0, stream>>>(
            h1, (int)D, B * D, w2t + (size_t)g0 * D * D, (int)D, D * D,
            b2 + (size_t)g0 * D, D, h2, (int)D, B * D, (int)D);
        ln_out_kernel<<<(int)B, 256, 0, stream>>>(h2, gate, ln_g, ln_b, out, Eg, g0, g > 0 ? 1 : 0);
    }
}